// Round 3
// baseline (1755.004 us; speedup 1.0000x reference)
//
#include <hip/hip_runtime.h>
#include <hip/hip_bf16.h>

#define B_ 256
#define T_ 8
#define E_ 1024
#define H_ 1024
#define L_ 8
#define KD 2048   // E+H
#define ND 4096   // 4*H, gate-interleaved n = 4*j + g  (g: 0=u,1=f,2=o,3=c~)

#define BM 256
#define BN 128
#define BK 64
#define KT (KD / BK)          // 32
// per-buffer LDS: A 256x64 bf16 packed (32768 B) + B 128x64 bf16 (16384 B)
#define ABYTES 32768
#define BUFBYTES 49152

// s_waitcnt immediates (gfx9 encoding): vm[3:0]|exp[6:4]|lgkm[11:8]|vm[5:4]<<14
#define WAITCNT_LGKM0 0xC07F   // lgkmcnt(0), vmcnt/exp unmasked

typedef __bf16 bf16x8 __attribute__((ext_vector_type(8)));
typedef float floatx4 __attribute__((ext_vector_type(4)));

__device__ __forceinline__ float sigm(float x) { return 1.f / (1.f + __expf(-x)); }
__device__ __forceinline__ float tanh_(float x) { return 1.f - 2.f / (__expf(2.f * x) + 1.f); }

// ---------------------------------------------------------------------------
// P1: Wu/Wf/Wo/Wc (L,2048,1024) fp32 -> WT[l][n][k] bf16, n = 4*j + g
// 64x64 tiles, float4 loads, 16B stores. grid = 8*4*32*16 = 16384 blocks.
// ---------------------------------------------------------------------------
__global__ __launch_bounds__(256) void prep_weights(
    const float* __restrict__ Wu, const float* __restrict__ Wf,
    const float* __restrict__ Wo, const float* __restrict__ Wc,
    __hip_bfloat16* __restrict__ WT)
{
    __shared__ float sm[64][65];
    int bid = blockIdx.x;
    int jt = bid & 15;
    int kt = (bid >> 4) & 31;
    int g  = (bid >> 9) & 3;
    int l  = bid >> 11;
    const float* src = (g == 0) ? Wu : (g == 1) ? Wf : (g == 2) ? Wo : Wc;
    int tid = threadIdx.x;
    int cr = tid >> 4;            // 0..15
    int cc = (tid & 15) * 4;      // 0..60
    const float* base = src + ((size_t)(l * KD + kt * 64)) * 1024 + jt * 64;
#pragma unroll
    for (int p = 0; p < 4; ++p) {
        int kr = p * 16 + cr;
        float4 v = *(const float4*)(base + (size_t)kr * 1024 + cc);
        sm[kr][cc] = v.x; sm[kr][cc + 1] = v.y; sm[kr][cc + 2] = v.z; sm[kr][cc + 3] = v.w;
    }
    __syncthreads();
    int kc8 = (tid & 7) * 8;
    int jr0 = tid >> 3;           // 0..31
#pragma unroll
    for (int p = 0; p < 2; ++p) {
        int jr = p * 32 + jr0;
        __hip_bfloat16 tmp[8];
#pragma unroll
        for (int i = 0; i < 8; ++i) tmp[i] = __float2bfloat16(sm[kc8 + i][jr]);
        size_t n = (size_t)(jt * 64 + jr) * 4 + g;
        *(uint4*)&WT[((size_t)l * ND + n) * KD + kt * 64 + kc8] = *(uint4*)tmp;
    }
}

// ---------------------------------------------------------------------------
// P2: x -> bf16; h0 -> bf16; c0 -> fp32 cbuf; biases -> interleaved bcat
// ---------------------------------------------------------------------------
__global__ __launch_bounds__(256) void prep_misc(
    const float* __restrict__ x,  const float* __restrict__ h0,
    const float* __restrict__ c0,
    const float* __restrict__ bu, const float* __restrict__ bfv,
    const float* __restrict__ bo, const float* __restrict__ bc,
    __hip_bfloat16* __restrict__ xbf, __hip_bfloat16* __restrict__ hb0,
    float* __restrict__ cbuf, float* __restrict__ bcat)
{
    size_t i = (size_t)blockIdx.x * 256 + threadIdx.x;
    const size_t NX = (size_t)B_ * T_ * E_;
    const size_t NH = (size_t)L_ * B_ * H_;
    if (i < NX) {
        xbf[i] = __float2bfloat16(x[i]);
    } else if (i < NX + NH) {
        size_t j = i - NX; hb0[j] = __float2bfloat16(h0[j]);
    } else if (i < NX + 2 * NH) {
        size_t j = i - NX - NH; cbuf[j] = c0[j];
    } else if (i < NX + 2 * NH + (size_t)L_ * ND) {
        size_t j = i - NX - 2 * NH;
        int l = (int)(j >> 12); int n = (int)(j & 4095);
        int jj = n >> 2; int g = n & 3;
        const float* bs = (g == 0) ? bu : (g == 1) ? bfv : (g == 2) ? bo : bc;
        bcat[j] = bs[l * 1024 + jj];
    }
}

// ---------------------------------------------------------------------------
// One diagonal d = t + l. 32 blocks per cell (n_blk), BM=256 covers all batch.
// 512 threads = 8 waves (wave grid 4m x 2n, wave tile 64x64 of 16x16x32 MFMA).
// Staging: buffer_load -> VGPR -> ds_write (precise vmcnt; avoids the
// global_load_lds/ds_read conservative-waitcnt serialization). Double-buffered
// LDS, ONE raw barrier per K-iter (manual lgkmcnt(0), no vmcnt drain):
//   iter kt: compute(buf kt%2) ; ds_write(buf kt%2^1 <- regs kt+1) ;
//            issue loads(kt+2) ; s_waitcnt lgkm(0) ; s_barrier
// ---------------------------------------------------------------------------
__global__ __launch_bounds__(512) void lstm_step(
    int d, int tmin,
    const __hip_bfloat16* __restrict__ xbf,
    const __hip_bfloat16* __restrict__ WT,
    const float* __restrict__ bcat,
    __hip_bfloat16* __restrict__ hb0,
    __hip_bfloat16* __restrict__ hb1,
    float* __restrict__ cbuf,
    float* __restrict__ out)
{
    __shared__ __align__(16) char smraw[2][BUFBYTES];   // 98304 B

    int cell = blockIdx.x >> 5;
    int nb   = blockIdx.x & 31;
    int t = tmin + cell;
    int l = d - t;

    const __hip_bfloat16* hread  = (t & 1) ? hb1 : hb0;
    __hip_bfloat16*       hwrite = (t & 1) ? hb0 : hb1;

    const __hip_bfloat16* A1; int sA1;
    if (l == 0) { A1 = xbf + (size_t)t * E_;               sA1 = T_ * E_; }
    else        { A1 = hwrite + (size_t)(l - 1) * B_ * H_; sA1 = H_; }
    const __hip_bfloat16* A2 = hread + (size_t)l * B_ * H_;
    const __hip_bfloat16* Bbase = WT + ((size_t)l * ND + (size_t)nb * BN) * KD;

    int tid  = threadIdx.x;
    int lane = tid & 63;
    int wid  = tid >> 6;
    int wm = (wid & 3) * 64;
    int wn = (wid >> 2) * 64;
    int lr   = lane & 15;
    int quad = lane >> 4;

    // ---- staging addresses (fixed per thread across K) ----
    int srow = tid >> 3;                      // 0..63
    int c    = (tid & 7) ^ (srow & 7);        // XOR-swizzled 16B-chunk index
    const __hip_bfloat16* pA1[4];
    const __hip_bfloat16* pA2[4];
    const __hip_bfloat16* pB[2];
#pragma unroll
    for (int s = 0; s < 4; ++s) {
        int row = s * 64 + srow;              // 0..255
        pA1[s] = A1 + (size_t)row * sA1 + c * 8;
        pA2[s] = A2 + (size_t)row * H_ + c * 8 - E_;
    }
#pragma unroll
    for (int s = 0; s < 2; ++s) {
        int row = s * 64 + srow;              // 0..127
        pB[s] = Bbase + (size_t)row * KD + c * 8;
    }
    int ldsOff = wid * 1024 + lane * 16;      // bytes, matches reader layout

    auto loadT = [&](int k0, uint4* ra, uint4* rb) {
        bool first = (k0 < E_);
#pragma unroll
        for (int s = 0; s < 4; ++s)
            ra[s] = *(const uint4*)((first ? pA1[s] : pA2[s]) + k0);
#pragma unroll
        for (int s = 0; s < 2; ++s)
            rb[s] = *(const uint4*)(pB[s] + k0);
    };
    auto writeT = [&](int buf, const uint4* ra, const uint4* rb) {
        char* dst = smraw[buf];
#pragma unroll
        for (int s = 0; s < 4; ++s)
            *(uint4*)(dst + s * 8192 + ldsOff) = ra[s];
#pragma unroll
        for (int s = 0; s < 2; ++s)
            *(uint4*)(dst + ABYTES + s * 8192 + ldsOff) = rb[s];
    };

    floatx4 acc[4][4];
    floatx4 zero = {0.f, 0.f, 0.f, 0.f};
#pragma unroll
    for (int mi = 0; mi < 4; ++mi)
#pragma unroll
        for (int ni = 0; ni < 4; ++ni) acc[mi][ni] = zero;

    auto compute = [&](const char* buf) {
        const __hip_bfloat16* sm  = (const __hip_bfloat16*)buf;
        const __hip_bfloat16* smB = sm + ABYTES / 2;
#pragma unroll
        for (int ks = 0; ks < 2; ++ks) {
            int xo = (((ks * 4 + quad) ^ (lr & 7)) * 8);
            bf16x8 af[4], bfr[4];
#pragma unroll
            for (int mi = 0; mi < 4; ++mi)
                af[mi] = *(const bf16x8*)&sm[(wm + mi * 16 + lr) * 64 + xo];
#pragma unroll
            for (int ni = 0; ni < 4; ++ni)
                bfr[ni] = *(const bf16x8*)&smB[(wn + ni * 16 + lr) * 64 + xo];
#pragma unroll
            for (int mi = 0; mi < 4; ++mi)
#pragma unroll
                for (int ni = 0; ni < 4; ++ni)
                    acc[mi][ni] = __builtin_amdgcn_mfma_f32_16x16x32_bf16(
                        af[mi], bfr[ni], acc[mi][ni], 0, 0, 0);
        }
    };

    // ---- pipeline prologue ----
    uint4 rA[2][4], rB[2][2];
    loadT(0, rA[0], rB[0]);
    writeT(0, rA[0], rB[0]);        // compiler inserts precise vmcnt waits
    loadT(BK, rA[1], rB[1]);        // tile 1 in flight
    __builtin_amdgcn_s_waitcnt(WAITCNT_LGKM0);
    __builtin_amdgcn_s_barrier();
    asm volatile("" ::: "memory");

    for (int kt = 0; kt < KT; ++kt) {
        int cur = kt & 1;
        compute(smraw[cur]);                               // reads buf cur
        if (kt < KT - 1) {
            writeT(cur ^ 1, rA[(kt + 1) & 1], rB[(kt + 1) & 1]);
            if (kt < KT - 2)
                loadT((kt + 2) * BK, rA[kt & 1], rB[kt & 1]);
        }
        __builtin_amdgcn_s_waitcnt(WAITCNT_LGKM0);         // ds ops drained
        __builtin_amdgcn_s_barrier();                      // publish buf cur^1
        asm volatile("" ::: "memory");
    }

    // ---- epilogue: 4 chunks of 64 rows through LDS sC ----
    float* outH  = out;
    float* outC  = out + (size_t)B_ * T_ * H_;
    float* outHt = out + 2 * (size_t)B_ * T_ * H_;
    float* outCt = outHt + (size_t)B_ * H_;
    auto sC = (float(*)[BN + 4])smraw[0];   // 64 x 132 fp32 = 33792 B

    for (int q = 0; q < 4; ++q) {
        __syncthreads();
        if ((wid & 3) == q) {
#pragma unroll
            for (int mi = 0; mi < 4; ++mi)
#pragma unroll
                for (int ni = 0; ni < 4; ++ni)
#pragma unroll
                    for (int r = 0; r < 4; ++r)
                        sC[mi * 16 + quad * 4 + r][wn + ni * 16 + lr] = acc[mi][ni][r];
        }
        __syncthreads();
#pragma unroll
        for (int s = 0; s < 4; ++s) {
            int p = tid + s * 512;
            int r  = p >> 5;
            int jj = p & 31;
            float4 v  = *(float4*)&sC[r][jj * 4];
            float4 bb = *(const float4*)&bcat[(size_t)l * ND + nb * BN + jj * 4];
            float u  = sigm(v.x + bb.x);
            float f  = sigm(v.y + bb.y);
            float o  = sigm(v.z + bb.z);
            float ct = tanh_(v.w + bb.w);
            int b = q * 64 + r;
            int j = nb * 32 + jj;
            size_t ci = ((size_t)l * B_ + b) * H_ + j;
            float cn = f * cbuf[ci] + u * ct;
            cbuf[ci] = cn;
            float hn = o * tanh_(cn);
            hwrite[ci] = __float2bfloat16(hn);
            if (l == L_ - 1) {
                size_t oi = ((size_t)b * T_ + t) * H_ + j;
                outH[oi] = hn;
                outC[oi] = cn;
                if (t == T_ - 1) {
                    outHt[(size_t)b * H_ + j] = hn;
                    outCt[(size_t)b * H_ + j] = cn;
                }
            }
        }
    }
}

// ---------------------------------------------------------------------------
extern "C" void kernel_launch(void* const* d_in, const int* in_sizes, int n_in,
                              void* d_out, int out_size, void* d_ws, size_t ws_size,
                              hipStream_t stream)
{
    const float* x   = (const float*)d_in[0];
    const float* h0  = (const float*)d_in[1];
    const float* c0  = (const float*)d_in[2];
    const float* Wu  = (const float*)d_in[3];
    const float* bu  = (const float*)d_in[4];
    const float* Wf  = (const float*)d_in[5];
    const float* bfv = (const float*)d_in[6];
    const float* Wo  = (const float*)d_in[7];
    const float* bo  = (const float*)d_in[8];
    const float* Wc  = (const float*)d_in[9];
    const float* bc  = (const float*)d_in[10];
    float* out = (float*)d_out;

    char* ws = (char*)d_ws;
    __hip_bfloat16* WT   = (__hip_bfloat16*)(ws);                 // 134217728
    float*          bcat = (float*)(ws + 134217728);              //    131072
    __hip_bfloat16* xbf  = (__hip_bfloat16*)(ws + 134348800);     //   4194304
    __hip_bfloat16* hb0  = (__hip_bfloat16*)(ws + 138543104);     //   4194304
    __hip_bfloat16* hb1  = (__hip_bfloat16*)(ws + 142737408);     //   4194304
    float*          cbuf = (float*)(ws + 146931712);              //   8388608

    hipLaunchKernelGGL(prep_weights, dim3(16384), dim3(256), 0, stream,
                       Wu, Wf, Wo, Wc, WT);
    size_t n2 = (size_t)2097152 * 3 + (size_t)L_ * ND;
    hipLaunchKernelGGL(prep_misc, dim3((unsigned)((n2 + 255) / 256)), dim3(256), 0, stream,
                       x, h0, c0, bu, bfv, bo, bc, xbf, hb0, cbuf, bcat);

    for (int dg = 0; dg <= (T_ - 1) + (L_ - 1); ++dg) {
        int tmin = dg > L_ - 1 ? dg - (L_ - 1) : 0;
        int tmax = dg < T_ - 1 ? dg : T_ - 1;
        int nc = tmax - tmin + 1;
        hipLaunchKernelGGL(lstm_step, dim3(nc * 32), dim3(512), 0, stream,
                           dg, tmin, xbf, WT, bcat, hb0, hb1, cbuf, out);
    }
}

// Round 4
// 1488.934 us; speedup vs baseline: 1.1787x; 1.1787x over previous
//
#include <hip/hip_runtime.h>
#include <hip/hip_bf16.h>

#define B_ 256
#define T_ 8
#define E_ 1024
#define H_ 1024
#define L_ 8
#define KD 2048   // E+H
#define ND 4096   // 4*H, gate-interleaved n = 4*j + g  (g: 0=u,1=f,2=o,3=c~)

#define BM 256
#define BN 128
#define BK 64
#define KT (KD / BK)          // 32
// per-buffer LDS: A 256x64 bf16 packed (32768 B) + B 128x64 bf16 (16384 B)
#define ABYTES 32768
#define BUFBYTES 49152

// s_waitcnt immediate: lgkmcnt(0), vmcnt/exp unmasked
#define WAITCNT_LGKM0 0xC07F

#define SYNC() do {                                   \
    asm volatile("" ::: "memory");                    \
    __builtin_amdgcn_s_waitcnt(WAITCNT_LGKM0);        \
    __builtin_amdgcn_s_barrier();                     \
    asm volatile("" ::: "memory");                    \
} while (0)

typedef __bf16 bf16x8 __attribute__((ext_vector_type(8)));
typedef float floatx4 __attribute__((ext_vector_type(4)));

__device__ __forceinline__ float sigm(float x) { return 1.f / (1.f + __expf(-x)); }
__device__ __forceinline__ float tanh_(float x) { return 1.f - 2.f / (__expf(2.f * x) + 1.f); }

// ---------------------------------------------------------------------------
// P1: Wu/Wf/Wo/Wc (L,2048,1024) fp32 -> WT[l][n][k] bf16, n = 4*j + g
// ---------------------------------------------------------------------------
__global__ __launch_bounds__(256) void prep_weights(
    const float* __restrict__ Wu, const float* __restrict__ Wf,
    const float* __restrict__ Wo, const float* __restrict__ Wc,
    __hip_bfloat16* __restrict__ WT)
{
    __shared__ float sm[64][65];
    int bid = blockIdx.x;
    int jt = bid & 15;
    int kt = (bid >> 4) & 31;
    int g  = (bid >> 9) & 3;
    int l  = bid >> 11;
    const float* src = (g == 0) ? Wu : (g == 1) ? Wf : (g == 2) ? Wo : Wc;
    int tid = threadIdx.x;
    int cr = tid >> 4;            // 0..15
    int cc = (tid & 15) * 4;      // 0..60
    const float* base = src + ((size_t)(l * KD + kt * 64)) * 1024 + jt * 64;
#pragma unroll
    for (int p = 0; p < 4; ++p) {
        int kr = p * 16 + cr;
        float4 v = *(const float4*)(base + (size_t)kr * 1024 + cc);
        sm[kr][cc] = v.x; sm[kr][cc + 1] = v.y; sm[kr][cc + 2] = v.z; sm[kr][cc + 3] = v.w;
    }
    __syncthreads();
    int kc8 = (tid & 7) * 8;
    int jr0 = tid >> 3;           // 0..31
#pragma unroll
    for (int p = 0; p < 2; ++p) {
        int jr = p * 32 + jr0;
        __hip_bfloat16 tmp[8];
#pragma unroll
        for (int i = 0; i < 8; ++i) tmp[i] = __float2bfloat16(sm[kc8 + i][jr]);
        size_t n = (size_t)(jt * 64 + jr) * 4 + g;
        *(uint4*)&WT[((size_t)l * ND + n) * KD + kt * 64 + kc8] = *(uint4*)tmp;
    }
}

// ---------------------------------------------------------------------------
// P2: x -> bf16; h0 -> bf16; c0 -> fp32 cbuf; biases -> interleaved bcat
// ---------------------------------------------------------------------------
__global__ __launch_bounds__(256) void prep_misc(
    const float* __restrict__ x,  const float* __restrict__ h0,
    const float* __restrict__ c0,
    const float* __restrict__ bu, const float* __restrict__ bfv,
    const float* __restrict__ bo, const float* __restrict__ bc,
    __hip_bfloat16* __restrict__ xbf, __hip_bfloat16* __restrict__ hb0,
    float* __restrict__ cbuf, float* __restrict__ bcat)
{
    size_t i = (size_t)blockIdx.x * 256 + threadIdx.x;
    const size_t NX = (size_t)B_ * T_ * E_;
    const size_t NH = (size_t)L_ * B_ * H_;
    if (i < NX) {
        xbf[i] = __float2bfloat16(x[i]);
    } else if (i < NX + NH) {
        size_t j = i - NX; hb0[j] = __float2bfloat16(h0[j]);
    } else if (i < NX + 2 * NH) {
        size_t j = i - NX - NH; cbuf[j] = c0[j];
    } else if (i < NX + 2 * NH + (size_t)L_ * ND) {
        size_t j = i - NX - 2 * NH;
        int l = (int)(j >> 12); int n = (int)(j & 4095);
        int jj = n >> 2; int g = n & 3;
        const float* bs = (g == 0) ? bu : (g == 1) ? bfv : (g == 2) ? bo : bc;
        bcat[j] = bs[l * 1024 + jj];
    }
}

// ---------------------------------------------------------------------------
// One diagonal d = t + l. 32 blocks per cell (n_blk), BM=256 covers all batch.
// 512 threads = 8 waves (wave grid 4m x 2n, wave tile 64x64 of 16x16x32 MFMA).
// Staging: buffer_load -> named VGPR sets -> ds_write (precise per-reg vmcnt;
// no global_load_lds aliasing stall, no dynamic private-array indexing).
// Manually 2x-unrolled ping-pong: literal LDS pointers, one lgkm-only
// barrier per K-iter, loads issued 2 tiles ahead.
// ---------------------------------------------------------------------------
__global__ __launch_bounds__(512) void lstm_step(
    int d, int tmin,
    const __hip_bfloat16* __restrict__ xbf,
    const __hip_bfloat16* __restrict__ WT,
    const float* __restrict__ bcat,
    __hip_bfloat16* __restrict__ hb0,
    __hip_bfloat16* __restrict__ hb1,
    float* __restrict__ cbuf,
    float* __restrict__ out)
{
    __shared__ __align__(16) char smraw[2][BUFBYTES];   // 98304 B

    int cell = blockIdx.x >> 5;
    int nb   = blockIdx.x & 31;
    int t = tmin + cell;
    int l = d - t;

    const __hip_bfloat16* hread  = (t & 1) ? hb1 : hb0;
    __hip_bfloat16*       hwrite = (t & 1) ? hb0 : hb1;

    const __hip_bfloat16* A1; int sA1;
    if (l == 0) { A1 = xbf + (size_t)t * E_;               sA1 = T_ * E_; }
    else        { A1 = hwrite + (size_t)(l - 1) * B_ * H_; sA1 = H_; }
    const __hip_bfloat16* A2 = hread + (size_t)l * B_ * H_;
    const __hip_bfloat16* Bbase = WT + ((size_t)l * ND + (size_t)nb * BN) * KD;

    int tid  = threadIdx.x;
    int lane = tid & 63;
    int wid  = tid >> 6;
    int wm = (wid & 3) * 64;
    int wn = (wid >> 2) * 64;
    int lr   = lane & 15;
    int quad = lane >> 4;

    // ---- staging addresses: 3 base pointers, sections via const offsets ----
    int srow = tid >> 3;                      // 0..63
    int c    = (tid & 7) ^ (srow & 7);        // XOR-swizzled 16B-chunk index
    int s64A1 = 64 * sA1;                     // uniform
    const __hip_bfloat16* pA1b = A1 + (size_t)srow * sA1 + c * 8;
    const __hip_bfloat16* pA2b = A2 + (size_t)srow * H_  + c * 8 - E_;
    const __hip_bfloat16* pBb  = Bbase + (size_t)srow * KD + c * 8;
    int ldsOff = wid * 1024 + lane * 16;      // bytes = srow*128 + (lane&7)*16

    auto loadT = [&](int k0, uint4* ra, uint4* rb) {
        if (k0 < E_) {
#pragma unroll
            for (int s = 0; s < 4; ++s)
                ra[s] = *(const uint4*)(pA1b + s * s64A1 + k0);
        } else {
#pragma unroll
            for (int s = 0; s < 4; ++s)
                ra[s] = *(const uint4*)(pA2b + s * (64 * H_) + k0);
        }
#pragma unroll
        for (int s = 0; s < 2; ++s)
            rb[s] = *(const uint4*)(pBb + s * (64 * KD) + k0);
    };
    auto writeT = [&](char* dst, const uint4* ra, const uint4* rb) {
#pragma unroll
        for (int s = 0; s < 4; ++s)
            *(uint4*)(dst + s * 8192 + ldsOff) = ra[s];
#pragma unroll
        for (int s = 0; s < 2; ++s)
            *(uint4*)(dst + ABYTES + s * 8192 + ldsOff) = rb[s];
    };

    floatx4 acc[4][4];
    floatx4 zero = {0.f, 0.f, 0.f, 0.f};
#pragma unroll
    for (int mi = 0; mi < 4; ++mi)
#pragma unroll
        for (int ni = 0; ni < 4; ++ni) acc[mi][ni] = zero;

    auto compute = [&](const char* buf) {
        const __hip_bfloat16* sm  = (const __hip_bfloat16*)buf;
        const __hip_bfloat16* smB = sm + ABYTES / 2;
#pragma unroll
        for (int ks = 0; ks < 2; ++ks) {
            int xo = (((ks * 4 + quad) ^ (lr & 7)) * 8);
            bf16x8 af[4], bfr[4];
#pragma unroll
            for (int mi = 0; mi < 4; ++mi)
                af[mi] = *(const bf16x8*)&sm[(wm + mi * 16 + lr) * 64 + xo];
#pragma unroll
            for (int ni = 0; ni < 4; ++ni)
                bfr[ni] = *(const bf16x8*)&smB[(wn + ni * 16 + lr) * 64 + xo];
#pragma unroll
            for (int mi = 0; mi < 4; ++mi)
#pragma unroll
                for (int ni = 0; ni < 4; ++ni)
                    acc[mi][ni] = __builtin_amdgcn_mfma_f32_16x16x32_bf16(
                        af[mi], bfr[ni], acc[mi][ni], 0, 0, 0);
        }
    };

    // ---- pipeline prologue: buf0 <- tile0; a1/b1 <- tile1 in flight ----
    uint4 a0[4], a1[4], b0[2], b1[2];
    loadT(0, a0, b0);
    writeT(smraw[0], a0, b0);       // compiler inserts precise vmcnt waits
    loadT(BK, a1, b1);
    SYNC();

    // ---- main loop: 15 double-iters, computes tiles 0..29 ----
    for (int kt = 0; kt < KT - 2; kt += 2) {
        compute(smraw[0]);                     // tile kt
        writeT(smraw[1], a1, b1);              // tile kt+1 -> buf1
        loadT((kt + 2) * BK, a0, b0);          // tile kt+2 in flight
        SYNC();
        compute(smraw[1]);                     // tile kt+1
        writeT(smraw[0], a0, b0);              // tile kt+2 -> buf0
        loadT((kt + 3) * BK, a1, b1);          // tile kt+3 in flight
        SYNC();
    }
    // ---- drain: tiles 30, 31 ----
    compute(smraw[0]);                         // tile 30
    writeT(smraw[1], a1, b1);                  // tile 31 -> buf1
    SYNC();
    compute(smraw[1]);                         // tile 31

    // ---- epilogue: 4 chunks of 64 rows through LDS sC ----
    float* outH  = out;
    float* outC  = out + (size_t)B_ * T_ * H_;
    float* outHt = out + 2 * (size_t)B_ * T_ * H_;
    float* outCt = outHt + (size_t)B_ * H_;
    auto sC = (float(*)[BN + 4])smraw[0];   // 64 x 132 fp32 = 33792 B

    int jj = tid & 31;                       // invariant across s and q
    float4 bb = *(const float4*)&bcat[(size_t)l * ND + nb * BN + jj * 4];

    for (int q = 0; q < 4; ++q) {
        __syncthreads();
        if ((wid & 3) == q) {
#pragma unroll
            for (int mi = 0; mi < 4; ++mi)
#pragma unroll
                for (int ni = 0; ni < 4; ++ni)
#pragma unroll
                    for (int r = 0; r < 4; ++r)
                        sC[mi * 16 + quad * 4 + r][wn + ni * 16 + lr] = acc[mi][ni][r];
        }
        __syncthreads();
#pragma unroll
        for (int s = 0; s < 4; ++s) {
            int r = (tid >> 5) + s * 16;      // 0..63
            float4 v = *(float4*)&sC[r][jj * 4];
            float u  = sigm(v.x + bb.x);
            float f  = sigm(v.y + bb.y);
            float o  = sigm(v.z + bb.z);
            float ct = tanh_(v.w + bb.w);
            int b = q * 64 + r;
            int j = nb * 32 + jj;
            size_t ci = ((size_t)l * B_ + b) * H_ + j;
            float cn = f * cbuf[ci] + u * ct;
            cbuf[ci] = cn;
            float hn = o * tanh_(cn);
            hwrite[ci] = __float2bfloat16(hn);
            if (l == L_ - 1) {
                size_t oi = ((size_t)b * T_ + t) * H_ + j;
                outH[oi] = hn;
                outC[oi] = cn;
                if (t == T_ - 1) {
                    outHt[(size_t)b * H_ + j] = hn;
                    outCt[(size_t)b * H_ + j] = cn;
                }
            }
        }
    }
}

// ---------------------------------------------------------------------------
extern "C" void kernel_launch(void* const* d_in, const int* in_sizes, int n_in,
                              void* d_out, int out_size, void* d_ws, size_t ws_size,
                              hipStream_t stream)
{
    const float* x   = (const float*)d_in[0];
    const float* h0  = (const float*)d_in[1];
    const float* c0  = (const float*)d_in[2];
    const float* Wu  = (const float*)d_in[3];
    const float* bu  = (const float*)d_in[4];
    const float* Wf  = (const float*)d_in[5];
    const float* bfv = (const float*)d_in[6];
    const float* Wo  = (const float*)d_in[7];
    const float* bo  = (const float*)d_in[8];
    const float* Wc  = (const float*)d_in[9];
    const float* bc  = (const float*)d_in[10];
    float* out = (float*)d_out;

    char* ws = (char*)d_ws;
    __hip_bfloat16* WT   = (__hip_bfloat16*)(ws);                 // 134217728
    float*          bcat = (float*)(ws + 134217728);              //    131072
    __hip_bfloat16* xbf  = (__hip_bfloat16*)(ws + 134348800);     //   4194304
    __hip_bfloat16* hb0  = (__hip_bfloat16*)(ws + 138543104);     //   4194304
    __hip_bfloat16* hb1  = (__hip_bfloat16*)(ws + 142737408);     //   4194304
    float*          cbuf = (float*)(ws + 146931712);              //   8388608

    hipLaunchKernelGGL(prep_weights, dim3(16384), dim3(256), 0, stream,
                       Wu, Wf, Wo, Wc, WT);
    size_t n2 = (size_t)2097152 * 3 + (size_t)L_ * ND;
    hipLaunchKernelGGL(prep_misc, dim3((unsigned)((n2 + 255) / 256)), dim3(256), 0, stream,
                       x, h0, c0, bu, bfv, bo, bc, xbf, hb0, cbuf, bcat);

    for (int dg = 0; dg <= (T_ - 1) + (L_ - 1); ++dg) {
        int tmin = dg > L_ - 1 ? dg - (L_ - 1) : 0;
        int tmax = dg < T_ - 1 ? dg : T_ - 1;
        int nc = tmax - tmin + 1;
        hipLaunchKernelGGL(lstm_step, dim3(nc * 32), dim3(512), 0, stream,
                           dg, tmin, xbf, WT, bcat, hb0, hb1, cbuf, out);
    }
}